// Round 4
// baseline (1347.600 us; speedup 1.0000x reference)
//
#include <hip/hip_runtime.h>
#include <hip/hip_bf16.h>

// ---------------------------------------------------------------------------
// Streaming GEMM: thread = one row, all COLS cols in registers.
// W read with wave-uniform indices -> compiler scalarizes to s_load (K$
// broadcast, free for the vector pipe). X streamed global->VGPR with
// one-chunk prefetch. No LDS, no barriers.
// ---------------------------------------------------------------------------
template<int COLS, int K, bool RELU_IN>
__global__ __launch_bounds__(256) void gemms_k(
    const float* __restrict__ X, const float* __restrict__ W,
    const float* __restrict__ bias, float* __restrict__ out,
    int nrows, float scale)
{
    constexpr int NC = K / 32;            // 32-k chunks
    int row = blockIdx.x * 256 + threadIdx.x;
    int r   = row < nrows ? row : nrows - 1;
    const float* Xp = X + (size_t)r * K;

    float acc[COLS];
    #pragma unroll
    for (int c = 0; c < COLS; ++c) acc[c] = 0.f;

    float4 t[8];
    #pragma unroll
    for (int q = 0; q < 8; ++q) t[q] = *(const float4*)&Xp[q * 4];

    #pragma unroll 1
    for (int kc = 0; kc < NC; ++kc) {
        float4 tn[8];
        if (kc < NC - 1) {
            #pragma unroll
            for (int q = 0; q < 8; ++q)
                tn[q] = *(const float4*)&Xp[(kc + 1) * 32 + q * 4];
        }
        #pragma unroll
        for (int q = 0; q < 8; ++q) {
            #pragma unroll
            for (int j = 0; j < 4; ++j) {
                float a = (j == 0) ? t[q].x : (j == 1) ? t[q].y
                        : (j == 2) ? t[q].z : t[q].w;
                if (RELU_IN) a = fmaxf(a, 0.f);
                int k = kc * 32 + q * 4 + j;
                #pragma unroll
                for (int c4 = 0; c4 < COLS / 4; ++c4) {
                    float4 w = *(const float4*)&W[(size_t)k * COLS + c4 * 4];
                    acc[c4 * 4 + 0] += a * w.x;
                    acc[c4 * 4 + 1] += a * w.y;
                    acc[c4 * 4 + 2] += a * w.z;
                    acc[c4 * 4 + 3] += a * w.w;
                }
            }
        }
        #pragma unroll
        for (int q = 0; q < 8; ++q) t[q] = tn[q];
    }

    if (row < nrows) {
        #pragma unroll
        for (int c4 = 0; c4 < COLS / 4; ++c4) {
            float4 o;
            o.x = acc[c4 * 4 + 0] * scale + (bias ? bias[c4 * 4 + 0] : 0.f);
            o.y = acc[c4 * 4 + 1] * scale + (bias ? bias[c4 * 4 + 1] : 0.f);
            o.z = acc[c4 * 4 + 2] * scale + (bias ? bias[c4 * 4 + 2] : 0.f);
            o.w = acc[c4 * 4 + 3] * scale + (bias ? bias[c4 * 4 + 3] : 0.f);
            *(float4*)&out[(size_t)row * COLS + c4 * 4] = o;
        }
    }
}

// ---------------------------------------------------------------------------
// Fused T-GEMM + classifier: thread = one row.
//   s = relu(T[row,:] @ eh + nfw[row] + bg)
//   c = relu(s @ Wc1 + bc1); logits = c @ Wc2 + bc2; out = softmax(logits)
// eh / Wc1 / Wc2 / biases read wave-uniform -> scalar loads. No LDS/barriers.
// ---------------------------------------------------------------------------
__global__ __launch_bounds__(256) void tfused_k(
    const float* __restrict__ T, const float* __restrict__ eh,
    const float* __restrict__ nfw, const float* __restrict__ bg,
    const float* __restrict__ Wc1, const float* __restrict__ bc1,
    const float* __restrict__ Wc2, const float* __restrict__ bc2,
    float* __restrict__ out, int nrows)
{
    int row = blockIdx.x * 256 + threadIdx.x;
    int r   = row < nrows ? row : nrows - 1;
    const float* Tp = T + (size_t)r * 1024;

    float acc[32];
    #pragma unroll
    for (int c = 0; c < 32; ++c) acc[c] = 0.f;

    float4 t[8];
    #pragma unroll
    for (int q = 0; q < 8; ++q) t[q] = *(const float4*)&Tp[q * 4];

    #pragma unroll 1
    for (int kc = 0; kc < 32; ++kc) {
        float4 tn[8];
        if (kc < 31) {
            #pragma unroll
            for (int q = 0; q < 8; ++q)
                tn[q] = *(const float4*)&Tp[(kc + 1) * 32 + q * 4];
        }
        #pragma unroll
        for (int q = 0; q < 8; ++q) {
            #pragma unroll
            for (int j = 0; j < 4; ++j) {
                float a = (j == 0) ? t[q].x : (j == 1) ? t[q].y
                        : (j == 2) ? t[q].z : t[q].w;
                int k = kc * 32 + q * 4 + j;
                #pragma unroll
                for (int c4 = 0; c4 < 8; ++c4) {
                    float4 w = *(const float4*)&eh[(size_t)k * 32 + c4 * 4];
                    acc[c4 * 4 + 0] += a * w.x;
                    acc[c4 * 4 + 1] += a * w.y;
                    acc[c4 * 4 + 2] += a * w.z;
                    acc[c4 * 4 + 3] += a * w.w;
                }
            }
        }
        #pragma unroll
        for (int q = 0; q < 8; ++q) t[q] = tn[q];
    }

    // shared = relu(acc + nfw + bg)
    #pragma unroll
    for (int c4 = 0; c4 < 8; ++c4) {
        float4 nf = *(const float4*)&nfw[(size_t)r * 32 + c4 * 4];
        acc[c4 * 4 + 0] = fmaxf(acc[c4 * 4 + 0] + nf.x + bg[c4 * 4 + 0], 0.f);
        acc[c4 * 4 + 1] = fmaxf(acc[c4 * 4 + 1] + nf.y + bg[c4 * 4 + 1], 0.f);
        acc[c4 * 4 + 2] = fmaxf(acc[c4 * 4 + 2] + nf.z + bg[c4 * 4 + 2], 0.f);
        acc[c4 * 4 + 3] = fmaxf(acc[c4 * 4 + 3] + nf.w + bg[c4 * 4 + 3], 0.f);
    }

    // classifier
    float l0 = bc2[0], l1 = bc2[1];
    #pragma unroll
    for (int j = 0; j < 32; ++j) {
        float s = bc1[j];
        #pragma unroll
        for (int i = 0; i < 32; ++i)
            s += acc[i] * Wc1[i * 32 + j];
        s = fmaxf(s, 0.f);
        l0 += s * Wc2[j * 2 + 0];
        l1 += s * Wc2[j * 2 + 1];
    }

    if (row < nrows) {
        float p0 = 1.f / (1.f + __expf(l1 - l0));
        float p1 = 1.f / (1.f + __expf(l0 - l1));
        *(float2*)&out[(size_t)row * 2] = make_float2(p0, p1);
    }
}

// --------------------------- CSR construction ------------------------------
__global__ void hist_k(const int* __restrict__ dst, int* __restrict__ deg, int E)
{
    int e = blockIdx.x * 256 + threadIdx.x;
    if (e < E) atomicAdd(&deg[dst[e]], 1);
}

__global__ void scan1_k(const int* __restrict__ deg, int* __restrict__ bsum, int N)
{
    __shared__ int s[256];
    int t = threadIdx.x, i = blockIdx.x * 256 + t;
    s[t] = (i < N) ? deg[i] : 0;
    __syncthreads();
    for (int off = 128; off > 0; off >>= 1) {
        if (t < off) s[t] += s[t + off];
        __syncthreads();
    }
    if (t == 0) bsum[blockIdx.x] = s[0];
}

__global__ void scan2_k(const int* __restrict__ bsum, int* __restrict__ boff,
                        int NB, int* __restrict__ rsN)
{
    __shared__ int s[256];
    int t = threadIdx.x;
    int v = (t < NB) ? bsum[t] : 0;
    s[t] = v;
    __syncthreads();
    for (int off = 1; off < 256; off <<= 1) {
        int u = (t >= off) ? s[t - off] : 0;
        __syncthreads();
        s[t] += u;
        __syncthreads();
    }
    if (t < NB) boff[t] = s[t] - v;
    if (t == NB - 1) *rsN = s[t];
}

__global__ void scan3_k(const int* __restrict__ deg, const int* __restrict__ boff,
                        int* __restrict__ rs, int* __restrict__ cur, int N)
{
    __shared__ int s[256];
    int t = threadIdx.x, i = blockIdx.x * 256 + t;
    int v = (i < N) ? deg[i] : 0;
    s[t] = v;
    __syncthreads();
    for (int off = 1; off < 256; off <<= 1) {
        int u = (t >= off) ? s[t - off] : 0;
        __syncthreads();
        s[t] += u;
        __syncthreads();
    }
    if (i < N) {
        int ex = boff[blockIdx.x] + s[t] - v;
        rs[i] = ex;
        cur[i] = ex;
    }
}

// packed (src, weight-bits) per CSR slot: one 8B store instead of two 4B
__global__ void fill_k(const int* __restrict__ src, const int* __restrict__ dst,
                       const float* __restrict__ ew, int* __restrict__ cur,
                       int2* __restrict__ epk, int E)
{
    int e = blockIdx.x * 256 + threadIdx.x;
    if (e < E) {
        int pos = atomicAdd(&cur[dst[e]], 1);
        epk[pos] = make_int2(src[e], __float_as_int(ew[e]));
    }
}

// --------------------------- CSR gathers -----------------------------------
// Wave per node; 2x4 edge-slots in flight x 16 float4 feature chunks.
__global__ __launch_bounds__(256) void gather64_k(
    const float* __restrict__ hp, const int2* __restrict__ epk,
    const int* __restrict__ rs, float* __restrict__ outv, int N)
{
    int lane = threadIdx.x & 63;
    int sub  = lane >> 4;
    int ch   = lane & 15;
    int wid  = (blockIdx.x * blockDim.x + threadIdx.x) >> 6;
    int nw   = (gridDim.x * blockDim.x) >> 6;
    for (int n = wid; n < N; n += nw) {
        int j0 = rs[n], j1 = rs[n + 1];
        float4 acc = make_float4(0.f, 0.f, 0.f, 0.f);
        for (int j = j0; j < j1; j += 8) {
            int ja = j + sub, jb = j + 4 + sub;
            bool va = ja < j1, vb = jb < j1;
            int2 ea = epk[va ? ja : j0];
            int2 eb = epk[vb ? jb : j0];
            float wa = va ? __int_as_float(ea.y) : 0.f;
            float wb = vb ? __int_as_float(eb.y) : 0.f;
            float4 v1 = *(const float4*)&hp[(size_t)ea.x * 64 + ch * 4];
            float4 v2 = *(const float4*)&hp[(size_t)eb.x * 64 + ch * 4];
            acc.x += v1.x * wa + v2.x * wb;
            acc.y += v1.y * wa + v2.y * wb;
            acc.z += v1.z * wa + v2.z * wb;
            acc.w += v1.w * wa + v2.w * wb;
        }
        acc.x += __shfl_xor(acc.x, 16); acc.y += __shfl_xor(acc.y, 16);
        acc.z += __shfl_xor(acc.z, 16); acc.w += __shfl_xor(acc.w, 16);
        acc.x += __shfl_xor(acc.x, 32); acc.y += __shfl_xor(acc.y, 32);
        acc.z += __shfl_xor(acc.z, 32); acc.w += __shfl_xor(acc.w, 32);
        if (lane < 16)
            *(float4*)&outv[(size_t)n * 64 + ch * 4] = acc;
    }
}

// Wave per node; 2x8 edge-slots in flight x 8 float4 chunks.
template<bool WEIGHTED, bool RELU>
__global__ __launch_bounds__(256) void gather32_k(
    const float* __restrict__ hp, const int2* __restrict__ epk,
    const int* __restrict__ rs, float* __restrict__ outv, int N)
{
    int lane = threadIdx.x & 63;
    int sub  = lane >> 3;
    int ch   = lane & 7;
    int wid  = (blockIdx.x * blockDim.x + threadIdx.x) >> 6;
    int nw   = (gridDim.x * blockDim.x) >> 6;
    for (int n = wid; n < N; n += nw) {
        int j0 = rs[n], j1 = rs[n + 1];
        float4 acc = make_float4(0.f, 0.f, 0.f, 0.f);
        for (int j = j0; j < j1; j += 16) {
            int ja = j + sub, jb = j + 8 + sub;
            bool va = ja < j1, vb = jb < j1;
            int2 ea = epk[va ? ja : j0];
            int2 eb = epk[vb ? jb : j0];
            float wa = WEIGHTED ? __int_as_float(ea.y) : 1.f;
            float wb = WEIGHTED ? __int_as_float(eb.y) : 1.f;
            if (!va) wa = 0.f;
            if (!vb) wb = 0.f;
            float4 v1 = *(const float4*)&hp[(size_t)ea.x * 32 + ch * 4];
            float4 v2 = *(const float4*)&hp[(size_t)eb.x * 32 + ch * 4];
            if (RELU) {
                v1.x = fmaxf(v1.x, 0.f); v1.y = fmaxf(v1.y, 0.f);
                v1.z = fmaxf(v1.z, 0.f); v1.w = fmaxf(v1.w, 0.f);
                v2.x = fmaxf(v2.x, 0.f); v2.y = fmaxf(v2.y, 0.f);
                v2.z = fmaxf(v2.z, 0.f); v2.w = fmaxf(v2.w, 0.f);
            }
            acc.x += v1.x * wa + v2.x * wb;
            acc.y += v1.y * wa + v2.y * wb;
            acc.z += v1.z * wa + v2.z * wb;
            acc.w += v1.w * wa + v2.w * wb;
        }
        acc.x += __shfl_xor(acc.x, 8);  acc.y += __shfl_xor(acc.y, 8);
        acc.z += __shfl_xor(acc.z, 8);  acc.w += __shfl_xor(acc.w, 8);
        acc.x += __shfl_xor(acc.x, 16); acc.y += __shfl_xor(acc.y, 16);
        acc.z += __shfl_xor(acc.z, 16); acc.w += __shfl_xor(acc.w, 16);
        acc.x += __shfl_xor(acc.x, 32); acc.y += __shfl_xor(acc.y, 32);
        acc.z += __shfl_xor(acc.z, 32); acc.w += __shfl_xor(acc.w, 32);
        if (lane < 8)
            *(float4*)&outv[(size_t)n * 32 + ch * 4] = acc;
    }
}

// ----------------------- small edge-side matmuls ---------------------------
__global__ void efwe_k(const float* __restrict__ ef, const float* __restrict__ We,
                       float* __restrict__ tmp)
{
    int idx = blockIdx.x * 256 + threadIdx.x;
    int row = idx >> 5, c = idx & 31;
    float s = 0.f;
    #pragma unroll
    for (int k = 0; k < 64; ++k)
        s += ef[row * 64 + k] * We[k * 32 + c];
    tmp[row * 32 + c] = s;
}

__global__ void adjmm_k(const float* __restrict__ adj, const float* __restrict__ tmp,
                        float* __restrict__ edge_h)
{
    int kq     = blockIdx.x & 3;
    int rowblk = blockIdx.x >> 2;
    int r = rowblk * 8 + (threadIdx.x >> 5);
    int c = threadIdx.x & 31;
    float s = 0.f;
    int k0 = kq * 256;
    #pragma unroll 8
    for (int k = k0; k < k0 + 256; ++k)
        s += adj[r * 1024 + k] * tmp[k * 32 + c];
    atomicAdd(&edge_h[r * 32 + c], s);
}

// ---------------------------------------------------------------------------
extern "C" void kernel_launch(void* const* d_in, const int* in_sizes, int n_in,
                              void* d_out, int out_size, void* d_ws, size_t ws_size,
                              hipStream_t stream)
{
    const float* x   = (const float*)d_in[0];
    const int*   ei  = (const int*)  d_in[1];
    const float* ew  = (const float*)d_in[2];
    const float* ef  = (const float*)d_in[3];
    const float* adj = (const float*)d_in[4];
    const float* T   = (const float*)d_in[5];
    const float* W1  = (const float*)d_in[6];
    const float* b1  = (const float*)d_in[7];
    const float* W2  = (const float*)d_in[8];
    const float* b2  = (const float*)d_in[9];
    const float* Wn  = (const float*)d_in[10];
    const float* We  = (const float*)d_in[11];
    const float* bg  = (const float*)d_in[12];
    const float* Wc1 = (const float*)d_in[13];
    const float* bc1 = (const float*)d_in[14];
    const float* Wc2 = (const float*)d_in[15];
    const float* bc2 = (const float*)d_in[16];
    float* out = (float*)d_out;

    const int N = in_sizes[0] / 128;   // 50000
    const int E = in_sizes[1] / 2;     // 1000000
    const int* srcIdx = ei;
    const int* dstIdx = ei + E;

    // ---- workspace layout (floats) ----
    float* ws = (float*)d_ws;
    size_t o = 0;
    float* h1acc  = ws + o; o += (size_t)N * 64;
    float* h2acc  = ws + o; o += (size_t)N * 32;
    float* nfacc  = ws + o; o += (size_t)N * 32;
    float* edge_h = ws + o; o += 1024 * 32;
    float* tmp    = ws + o; o += 1024 * 32;
    float* nfw    = ws + o; o += (size_t)N * 32;
    float* h1p    = ws + o; o += (size_t)N * 64;
    float* h2p    = ws + o; o += (size_t)N * 32;
    int2*  epk    = (int2*)(ws + o);  o += (size_t)E * 2;
    int*   deg    = (int*)(ws + o);   o += N;
    int*   rs     = (int*)(ws + o);   o += N + 1;
    int*   cur    = (int*)(ws + o);   o += N + 1;
    int*   bsum   = (int*)(ws + o);   o += 256;
    int*   boff   = (int*)(ws + o);   o += 256;

    const int NB = (N + 255) / 256;   // 196

    (void)hipMemsetAsync(deg, 0, (size_t)N * sizeof(int), stream);
    (void)hipMemsetAsync(edge_h, 0, 1024 * 32 * sizeof(float), stream);

    // 1. h1p = x @ W1 + b1
    gemms_k<64, 128, false><<<NB, 256, 0, stream>>>(x, W1, b1, h1p, N, 1.f);

    // 2. CSR build
    hist_k<<<(E + 255) / 256, 256, 0, stream>>>(dstIdx, deg, E);
    scan1_k<<<NB, 256, 0, stream>>>(deg, bsum, N);
    scan2_k<<<1, 256, 0, stream>>>(bsum, boff, NB, rs + N);
    scan3_k<<<NB, 256, 0, stream>>>(deg, boff, rs, cur, N);
    fill_k<<<(E + 255) / 256, 256, 0, stream>>>(srcIdx, dstIdx, ew, cur, epk, E);

    // 3. h1acc[n] = sum_{e: dst=n} w_e * h1p[src_e]
    gather64_k<<<1024, 256, 0, stream>>>(h1p, epk, rs, h1acc, N);

    // 4. h2p = relu(h1acc) @ W2 + b2
    gemms_k<32, 64, true><<<NB, 256, 0, stream>>>(h1acc, W2, b2, h2p, N, 1.f);

    // 5. h2acc[n] = sum w_e * h2p[src_e]
    gather32_k<true, false><<<1024, 256, 0, stream>>>(h2p, epk, rs, h2acc, N);

    // 6. nfacc[n] = sum relu(h2acc)[src_e]
    gather32_k<false, true><<<1024, 256, 0, stream>>>(h2acc, epk, rs, nfacc, N);

    // 7. edge_h = adj_e @ (ef @ We)
    efwe_k<<<128, 256, 0, stream>>>(ef, We, tmp);
    adjmm_k<<<512, 256, 0, stream>>>(adj, tmp, edge_h);

    // 8. nfw = (nfacc / E) @ Wn
    gemms_k<32, 32, false><<<NB, 256, 0, stream>>>(nfacc, Wn, nullptr, nfw, N, 1.f / (float)E);

    // 9+10. out = softmax(classifier(relu(T @ edge_h + nfw + bg)))  (fused)
    tfused_k<<<NB, 256, 0, stream>>>(T, edge_h, nfw, bg, Wc1, bc1, Wc2, bc2, out, N);
}

// Round 5
// 702.750 us; speedup vs baseline: 1.9176x; 1.9176x over previous
//
#include <hip/hip_runtime.h>
#include <hip/hip_bf16.h>

#define RPB 256   // rows per block in tiled GEMM

// ---------------------------------------------------------------------------
// Tiled row-blocked GEMM (three small N×K@K×C projections). Proven in R2/R3.
// ---------------------------------------------------------------------------
template<int COLS, int K>
__global__ __launch_bounds__(256) void gemm_k(
    const float* __restrict__ X, const float* __restrict__ W,
    const float* __restrict__ bias, float* __restrict__ out,
    int nrows, float scale, int relu_in)
{
    constexpr int CPT = COLS / 8;
    constexpr int KT  = 32;
    constexpr int NKT = K / KT;

    __shared__ float sx[RPB * 36];
    __shared__ float sWT[COLS * 33];

    const int tid = threadIdx.x;
    const int cg  = tid & 7;
    const int rg  = tid >> 3;
    const int r0  = blockIdx.x * RPB;

    float acc[8][CPT];
    #pragma unroll
    for (int r = 0; r < 8; ++r)
        #pragma unroll
        for (int c = 0; c < CPT; ++c) acc[r][c] = 0.f;

    for (int kt = 0; kt < NKT; ++kt) {
        #pragma unroll
        for (int j = 0; j < 8; ++j) {
            int i  = tid + j * 256;
            int r  = i >> 3;
            int k4 = i & 7;
            int gr = r0 + r; if (gr >= nrows) gr = nrows - 1;
            float4 v = *(const float4*)&X[(size_t)gr * K + kt * KT + k4 * 4];
            if (relu_in) {
                v.x = fmaxf(v.x, 0.f); v.y = fmaxf(v.y, 0.f);
                v.z = fmaxf(v.z, 0.f); v.w = fmaxf(v.w, 0.f);
            }
            if (scale != 1.f) { v.x *= scale; v.y *= scale; v.z *= scale; v.w *= scale; }
            *(float4*)&sx[r * 36 + k4 * 4] = v;
        }
        for (int i = tid; i < COLS * KT; i += 256) {
            int kl = i / COLS, c = i % COLS;
            sWT[c * 33 + kl] = W[(size_t)(kt * KT + kl) * COLS + c];
        }
        __syncthreads();

        #pragma unroll
        for (int k4 = 0; k4 < 8; ++k4) {
            float4 a[8];
            #pragma unroll
            for (int r = 0; r < 8; ++r)
                a[r] = *(const float4*)&sx[(r * 32 + rg) * 36 + k4 * 4];
            #pragma unroll
            for (int cc = 0; cc < CPT; ++cc) {
                int c = cg * CPT + cc;
                float w0 = sWT[c * 33 + k4 * 4 + 0];
                float w1 = sWT[c * 33 + k4 * 4 + 1];
                float w2 = sWT[c * 33 + k4 * 4 + 2];
                float w3 = sWT[c * 33 + k4 * 4 + 3];
                #pragma unroll
                for (int r = 0; r < 8; ++r)
                    acc[r][cc] += a[r].x * w0 + a[r].y * w1 + a[r].z * w2 + a[r].w * w3;
            }
        }
        __syncthreads();
    }

    #pragma unroll
    for (int r = 0; r < 8; ++r) {
        int row = r0 + r * 32 + rg;
        if (row < nrows) {
            #pragma unroll
            for (int cc4 = 0; cc4 < CPT / 4; ++cc4) {
                int c = cg * CPT + cc4 * 4;
                float4 o;
                o.x = acc[r][cc4 * 4 + 0] + (bias ? bias[c + 0] : 0.f);
                o.y = acc[r][cc4 * 4 + 1] + (bias ? bias[c + 1] : 0.f);
                o.z = acc[r][cc4 * 4 + 2] + (bias ? bias[c + 2] : 0.f);
                o.w = acc[r][cc4 * 4 + 3] + (bias ? bias[c + 3] : 0.f);
                *(float4*)&out[(size_t)row * COLS + c] = o;
            }
        }
    }
}

// ---------------------------------------------------------------------------
// T-GEMM (R3-proven): par[kq][n][32] = T[n, kq*256:+256] @ eh[kslice, 32]
// Thread = one row; eh slice in LDS (broadcast reads); T streamed with
// one-chunk prefetch; no barriers in K-loop.
// ---------------------------------------------------------------------------
__global__ __launch_bounds__(256, 4) void tgemm2_k(
    const float* __restrict__ T, const float* __restrict__ eh,
    float* __restrict__ par, int nrows)
{
    __shared__ float seh[256 * 32];   // 32 KB
    const int tid = threadIdx.x;
    const int ks  = blockIdx.y * 256;

    #pragma unroll
    for (int j = 0; j < 8; ++j) {
        int i = tid + j * 256;
        *(float4*)&seh[i * 4] = *(const float4*)&eh[(size_t)ks * 32 + (size_t)i * 4];
    }
    __syncthreads();

    int row = blockIdx.x * 256 + tid;
    int r   = row < nrows ? row : nrows - 1;
    const float* Tp = T + (size_t)r * 1024 + ks;

    float acc[32];
    #pragma unroll
    for (int c = 0; c < 32; ++c) acc[c] = 0.f;

    float4 t[8];
    #pragma unroll
    for (int q = 0; q < 8; ++q) t[q] = *(const float4*)&Tp[q * 4];

    for (int kc = 0; kc < 8; ++kc) {
        float4 tn[8];
        if (kc < 7) {
            #pragma unroll
            for (int q = 0; q < 8; ++q)
                tn[q] = *(const float4*)&Tp[(kc + 1) * 32 + q * 4];
        }
        #pragma unroll
        for (int q = 0; q < 8; ++q) {
            #pragma unroll
            for (int j = 0; j < 4; ++j) {
                float a = (j == 0) ? t[q].x : (j == 1) ? t[q].y : (j == 2) ? t[q].z : t[q].w;
                int k = kc * 32 + q * 4 + j;
                #pragma unroll
                for (int c4 = 0; c4 < 8; ++c4) {
                    float4 w = *(const float4*)&seh[k * 32 + c4 * 4];
                    acc[c4 * 4 + 0] += a * w.x;
                    acc[c4 * 4 + 1] += a * w.y;
                    acc[c4 * 4 + 2] += a * w.z;
                    acc[c4 * 4 + 3] += a * w.w;
                }
            }
        }
        #pragma unroll
        for (int q = 0; q < 8; ++q) t[q] = tn[q];
    }

    if (row < nrows) {
        float* p = par + (size_t)blockIdx.y * nrows * 32 + (size_t)row * 32;
        #pragma unroll
        for (int c4 = 0; c4 < 8; ++c4)
            *(float4*)&p[c4 * 4] = make_float4(acc[c4 * 4 + 0], acc[c4 * 4 + 1],
                                               acc[c4 * 4 + 2], acc[c4 * 4 + 3]);
    }
}

// ---------------------------------------------------------------------------
// Epilogue: shared = relu(sum_kq par + nfw + bg); classifier; softmax.
// ---------------------------------------------------------------------------
__global__ __launch_bounds__(256) void classify_k(
    const float* __restrict__ par, const float* __restrict__ nfw,
    const float* __restrict__ bg, const float* __restrict__ Wc1,
    const float* __restrict__ bc1, const float* __restrict__ Wc2,
    const float* __restrict__ bc2, float* __restrict__ out, int nrows)
{
    __shared__ float sWc1T[1024];
    __shared__ float sWc2[64];
    __shared__ float sb[66];

    int tid = threadIdx.x;
    for (int i = tid; i < 1024; i += 256)
        sWc1T[(i & 31) * 32 + (i >> 5)] = Wc1[i];
    if (tid < 64) sWc2[tid] = Wc2[tid];
    if (tid < 32)      sb[tid] = bc1[tid];
    else if (tid < 64) sb[tid] = bg[tid - 32];
    else if (tid < 66) sb[tid] = bc2[tid - 64];
    __syncthreads();

    int row = blockIdx.x * 256 + tid;
    if (row >= nrows) return;

    size_t stride = (size_t)nrows * 32;
    float4 sh4[8];
    #pragma unroll
    for (int i4 = 0; i4 < 8; ++i4) {
        const float* base = par + (size_t)row * 32 + i4 * 4;
        float4 v0 = *(const float4*)(base);
        float4 v1 = *(const float4*)(base + stride);
        float4 v2 = *(const float4*)(base + 2 * stride);
        float4 v3 = *(const float4*)(base + 3 * stride);
        float4 nf = *(const float4*)&nfw[(size_t)row * 32 + i4 * 4];
        float4 o;
        o.x = fmaxf(v0.x + v1.x + v2.x + v3.x + nf.x + sb[32 + i4 * 4 + 0], 0.f);
        o.y = fmaxf(v0.y + v1.y + v2.y + v3.y + nf.y + sb[32 + i4 * 4 + 1], 0.f);
        o.z = fmaxf(v0.z + v1.z + v2.z + v3.z + nf.z + sb[32 + i4 * 4 + 2], 0.f);
        o.w = fmaxf(v0.w + v1.w + v2.w + v3.w + nf.w + sb[32 + i4 * 4 + 3], 0.f);
        sh4[i4] = o;
    }

    float l0 = sb[64], l1 = sb[65];
    #pragma unroll
    for (int jj = 0; jj < 32; ++jj) {
        float s = sb[jj];
        #pragma unroll
        for (int i4 = 0; i4 < 8; ++i4) {
            float4 w4 = *(const float4*)&sWc1T[jj * 32 + i4 * 4];
            s += sh4[i4].x * w4.x + sh4[i4].y * w4.y
               + sh4[i4].z * w4.z + sh4[i4].w * w4.w;
        }
        s = fmaxf(s, 0.f);
        l0 += s * sWc2[jj * 2 + 0];
        l1 += s * sWc2[jj * 2 + 1];
    }
    float p0 = 1.f / (1.f + expf(l1 - l0));
    float p1 = 1.f / (1.f + expf(l0 - l1));
    *(float2*)&out[(size_t)row * 2] = make_float2(p0, p1);
}

// --------------------------- CSR construction ------------------------------
__global__ void hist_k(const int* __restrict__ dst, int* __restrict__ deg, int E)
{
    int e = blockIdx.x * 256 + threadIdx.x;
    if (e < E) atomicAdd(&deg[dst[e]], 1);
}

__global__ void scan1_k(const int* __restrict__ deg, int* __restrict__ bsum, int N)
{
    __shared__ int s[256];
    int t = threadIdx.x, i = blockIdx.x * 256 + t;
    s[t] = (i < N) ? deg[i] : 0;
    __syncthreads();
    for (int off = 128; off > 0; off >>= 1) {
        if (t < off) s[t] += s[t + off];
        __syncthreads();
    }
    if (t == 0) bsum[blockIdx.x] = s[0];
}

__global__ void scan2_k(const int* __restrict__ bsum, int* __restrict__ boff,
                        int NB, int* __restrict__ rsN)
{
    __shared__ int s[256];
    int t = threadIdx.x;
    int v = (t < NB) ? bsum[t] : 0;
    s[t] = v;
    __syncthreads();
    for (int off = 1; off < 256; off <<= 1) {
        int u = (t >= off) ? s[t - off] : 0;
        __syncthreads();
        s[t] += u;
        __syncthreads();
    }
    if (t < NB) boff[t] = s[t] - v;
    if (t == NB - 1) *rsN = s[t];
}

__global__ void scan3_k(const int* __restrict__ deg, const int* __restrict__ boff,
                        int* __restrict__ rs, int* __restrict__ cur, int N)
{
    __shared__ int s[256];
    int t = threadIdx.x, i = blockIdx.x * 256 + t;
    int v = (i < N) ? deg[i] : 0;
    s[t] = v;
    __syncthreads();
    for (int off = 1; off < 256; off <<= 1) {
        int u = (t >= off) ? s[t - off] : 0;
        __syncthreads();
        s[t] += u;
        __syncthreads();
    }
    if (i < N) {
        int ex = boff[blockIdx.x] + s[t] - v;
        rs[i] = ex;
        cur[i] = ex;
    }
}

// packed (src, weight-bits) per CSR slot
__global__ void fill_k(const int* __restrict__ src, const int* __restrict__ dst,
                       const float* __restrict__ ew, int* __restrict__ cur,
                       int2* __restrict__ epk, int E)
{
    int e = blockIdx.x * 256 + threadIdx.x;
    if (e < E) {
        int pos = atomicAdd(&cur[dst[e]], 1);
        epk[pos] = make_int2(src[e], __float_as_int(ew[e]));
    }
}

// --------------------------- CSR gathers -----------------------------------
// Thread = (node, float4-chunk). Plain sequential j-loop: epk addresses are
// sequential (compiler pipelines), rows coalesce across the chunk lanes,
// no shuffles, no slot padding. TLP from 12.5k/6.3k waves hides latency.
__global__ __launch_bounds__(256) void gather64_k(
    const float* __restrict__ hp, const int2* __restrict__ epk,
    const int* __restrict__ rs, float* __restrict__ outv, int N)
{
    int t = blockIdx.x * 256 + threadIdx.x;   // N*16 threads
    if (t >= N * 16) return;
    int n  = t >> 4;
    int ch = t & 15;
    int j0 = rs[n], j1 = rs[n + 1];
    float4 acc = make_float4(0.f, 0.f, 0.f, 0.f);
    for (int j = j0; j < j1; ++j) {
        int2 e = epk[j];
        float w = __int_as_float(e.y);
        float4 v = *(const float4*)&hp[(size_t)e.x * 64 + ch * 4];
        acc.x += v.x * w; acc.y += v.y * w;
        acc.z += v.z * w; acc.w += v.w * w;
    }
    *(float4*)&outv[(size_t)n * 64 + ch * 4] = acc;
}

template<bool WEIGHTED, bool RELU>
__global__ __launch_bounds__(256) void gather32_k(
    const float* __restrict__ hp, const int2* __restrict__ epk,
    const int* __restrict__ rs, float* __restrict__ outv, int N)
{
    int t = blockIdx.x * 256 + threadIdx.x;   // N*8 threads
    if (t >= N * 8) return;
    int n  = t >> 3;
    int ch = t & 7;
    int j0 = rs[n], j1 = rs[n + 1];
    float4 acc = make_float4(0.f, 0.f, 0.f, 0.f);
    for (int j = j0; j < j1; ++j) {
        int2 e = epk[j];
        float w = WEIGHTED ? __int_as_float(e.y) : 1.f;
        float4 v = *(const float4*)&hp[(size_t)e.x * 32 + ch * 4];
        if (RELU) {
            v.x = fmaxf(v.x, 0.f); v.y = fmaxf(v.y, 0.f);
            v.z = fmaxf(v.z, 0.f); v.w = fmaxf(v.w, 0.f);
        }
        acc.x += v.x * w; acc.y += v.y * w;
        acc.z += v.z * w; acc.w += v.w * w;
    }
    *(float4*)&outv[(size_t)n * 32 + ch * 4] = acc;
}

// ----------------------- small edge-side matmuls ---------------------------
__global__ void efwe_k(const float* __restrict__ ef, const float* __restrict__ We,
                       float* __restrict__ tmp)
{
    int idx = blockIdx.x * 256 + threadIdx.x;
    int row = idx >> 5, c = idx & 31;
    float s = 0.f;
    #pragma unroll
    for (int k = 0; k < 64; ++k)
        s += ef[row * 64 + k] * We[k * 32 + c];
    tmp[row * 32 + c] = s;
}

__global__ void adjmm_k(const float* __restrict__ adj, const float* __restrict__ tmp,
                        float* __restrict__ edge_h)
{
    int kq     = blockIdx.x & 3;
    int rowblk = blockIdx.x >> 2;
    int r = rowblk * 8 + (threadIdx.x >> 5);
    int c = threadIdx.x & 31;
    float s = 0.f;
    int k0 = kq * 256;
    #pragma unroll 8
    for (int k = k0; k < k0 + 256; ++k)
        s += adj[r * 1024 + k] * tmp[k * 32 + c];
    atomicAdd(&edge_h[r * 32 + c], s);
}

// ---------------------------------------------------------------------------
extern "C" void kernel_launch(void* const* d_in, const int* in_sizes, int n_in,
                              void* d_out, int out_size, void* d_ws, size_t ws_size,
                              hipStream_t stream)
{
    const float* x   = (const float*)d_in[0];
    const int*   ei  = (const int*)  d_in[1];
    const float* ew  = (const float*)d_in[2];
    const float* ef  = (const float*)d_in[3];
    const float* adj = (const float*)d_in[4];
    const float* T   = (const float*)d_in[5];
    const float* W1  = (const float*)d_in[6];
    const float* b1  = (const float*)d_in[7];
    const float* W2  = (const float*)d_in[8];
    const float* b2  = (const float*)d_in[9];
    const float* Wn  = (const float*)d_in[10];
    const float* We  = (const float*)d_in[11];
    const float* bg  = (const float*)d_in[12];
    const float* Wc1 = (const float*)d_in[13];
    const float* bc1 = (const float*)d_in[14];
    const float* Wc2 = (const float*)d_in[15];
    const float* bc2 = (const float*)d_in[16];
    float* out = (float*)d_out;

    const int N = in_sizes[0] / 128;   // 50000
    const int E = in_sizes[1] / 2;     // 1000000
    const int* srcIdx = ei;
    const int* dstIdx = ei + E;

    // ---- workspace layout (floats) — identical footprint to proven R3 ----
    float* ws = (float*)d_ws;
    size_t o = 0;
    float* h1acc  = ws + o; o += (size_t)N * 64;
    float* h2acc  = ws + o; o += (size_t)N * 32;
    float* nfacc  = ws + o; o += (size_t)N * 32;
    float* edge_h = ws + o; o += 1024 * 32;
    float* tmp    = ws + o; o += 1024 * 32;
    float* nfw    = ws + o; o += (size_t)N * 32;
    float* par    = ws + o; o += (size_t)N * 128;  // aliases h1p/h2p
    float* h1p    = par;                           // dead before tgemm writes
    float* h2p    = par + (size_t)N * 64;          // dead before tgemm writes
    int2*  epk    = (int2*)(ws + o);  o += (size_t)E * 2;
    int*   deg    = (int*)(ws + o);   o += N;
    int*   rs     = (int*)(ws + o);   o += N + 1;
    int*   cur    = (int*)(ws + o);   o += N + 1;
    int*   bsum   = (int*)(ws + o);   o += 256;
    int*   boff   = (int*)(ws + o);   o += 256;

    const int NB = (N + 255) / 256;   // 196

    (void)hipMemsetAsync(deg, 0, (size_t)N * sizeof(int), stream);
    (void)hipMemsetAsync(edge_h, 0, 1024 * 32 * sizeof(float), stream);

    // 1. h1p = x @ W1 + b1
    gemm_k<64, 128><<<NB, 256, 0, stream>>>(x, W1, b1, h1p, N, 1.f, 0);

    // 2. CSR build
    hist_k<<<(E + 255) / 256, 256, 0, stream>>>(dstIdx, deg, E);
    scan1_k<<<NB, 256, 0, stream>>>(deg, bsum, N);
    scan2_k<<<1, 256, 0, stream>>>(bsum, boff, NB, rs + N);
    scan3_k<<<NB, 256, 0, stream>>>(deg, boff, rs, cur, N);
    fill_k<<<(E + 255) / 256, 256, 0, stream>>>(srcIdx, dstIdx, ew, cur, epk, E);

    // 3. h1acc[n] = sum_{e: dst=n} w_e * h1p[src_e]
    gather64_k<<<(N * 16 + 255) / 256, 256, 0, stream>>>(h1p, epk, rs, h1acc, N);

    // 4. h2p = relu(h1acc) @ W2 + b2
    gemm_k<32, 64><<<NB, 256, 0, stream>>>(h1acc, W2, b2, h2p, N, 1.f, 1);

    // 5. h2acc[n] = sum w_e * h2p[src_e]
    gather32_k<true, false><<<(N * 8 + 255) / 256, 256, 0, stream>>>(h2p, epk, rs, h2acc, N);

    // 6. nfacc[n] = sum relu(h2acc)[src_e]
    gather32_k<false, true><<<(N * 8 + 255) / 256, 256, 0, stream>>>(h2acc, epk, rs, nfacc, N);

    // 7. edge_h = adj_e @ (ef @ We)
    efwe_k<<<128, 256, 0, stream>>>(ef, We, tmp);
    adjmm_k<<<512, 256, 0, stream>>>(adj, tmp, edge_h);

    // 8. nfw = (nfacc / E) @ Wn
    gemm_k<32, 32><<<NB, 256, 0, stream>>>(nfacc, Wn, nullptr, nfw, N, 1.f / (float)E, 0);

    // 9. par[kq] = T[:, kq*256:+256] @ edge_h[kslice]
    tgemm2_k<<<dim3(NB, 4), 256, 0, stream>>>(T, edge_h, par, N);

    // 10. out = softmax(classifier(relu(sum par + nfw + bg)))
    classify_k<<<NB, 256, 0, stream>>>(par, nfw, bg, Wc1, bc1, Wc2, bc2, out, N);
}